// Round 9
// baseline (62.681 us; speedup 1.0000x reference)
//
#include <hip/hip_runtime.h>
#include <hip/hip_bf16.h>
#include <math.h>

// v8: m97-style global_load_lds staging for BOTH x (fp32) and pre-packed
//     bf16 weights. 512 blocks x 512 thr (8 waves), 80KB LDS -> 2 blocks/CU
//     (independent barrier groups overlap each other's drains).
//  - prep_pack: weights -> bf16, K-tile-major, XOR-pre-swizzled chunks so
//    glds writes linear LDS and ds_read_b128 B-frags are conflict-free.
//  - L1: 13 K-tiles of 64; x[64][64]f32 + w1[128][64]bf16 both double-buffered,
//    staged entirely by glds issued BEFORE the MFMA phase of the previous tile.
//  - L2: w2 [256][32] tiles glds-staged (t0,t1 prefetched), h2/w3 overlay.
//  - Zero-padded weights make OOB x columns harmless (garbage x 0).

#define TPB 512

// packed weights in d_ws (shorts):
//  w1k [13 kt][128 row][8 chunk][8]  (chunk content pre-XOR'd by row&7)
//  w2k [4 kt][256 row][4 chunk][8]   (pre-XOR'd by row&3)
//  w3k [16 row][32 chunk][8]         (pre-XOR'd by row&7; rows >=10 zero)
#define W2K 106496
#define W3K 139264
#define NCHUNK_TOT 17920   // 13312 + 4096 + 512 (16B chunks)

typedef __attribute__((ext_vector_type(8))) short bf16x8;
typedef __attribute__((ext_vector_type(4))) float f32x4;

static __device__ inline short f2bf(float f) {
    union { float f; unsigned u; } v; v.f = f;
    unsigned r = v.u + 0x7fffu + ((v.u >> 16) & 1u);   // RNE
    return (short)(r >> 16);
}
static __device__ inline bf16x8 cvt8(float4 a, float4 b) {
    union { __hip_bfloat162 h2[4]; bf16x8 v; } u;
    u.h2[0] = __float22bfloat162_rn(make_float2(a.x, a.y));
    u.h2[1] = __float22bfloat162_rn(make_float2(a.z, a.w));
    u.h2[2] = __float22bfloat162_rn(make_float2(b.x, b.y));
    u.h2[3] = __float22bfloat162_rn(make_float2(b.z, b.w));
    return u.v;
}
static __device__ inline float4 ld4g(const float* p, bool ok) {
    return ok ? *reinterpret_cast<const float4*>(p) : make_float4(0.f,0.f,0.f,0.f);
}
static __device__ inline void gld16(const void* g, void* l) {
    __builtin_amdgcn_global_load_lds(
        (const __attribute__((address_space(1))) unsigned int*)g,
        (__attribute__((address_space(3))) unsigned int*)l, 16, 0, 0);
}

__global__ void prep_pack(const float* __restrict__ w1,
                          const float* __restrict__ w2,
                          const float* __restrict__ w3,
                          short* __restrict__ wb) {
    const int tid = blockIdx.x * blockDim.x + threadIdx.x;  // one per 16B chunk
    if (tid >= NCHUNK_TOT) return;
    float4 a = make_float4(0,0,0,0), b = a;
    size_t dst;
    if (tid < 13312) {            // w1k: kt = tid/1024, row = (tid%1024)/8, phys = tid%8
        const int kt = tid >> 10, rem = tid & 1023, row = rem >> 3, phys = rem & 7;
        const int kg = kt * 64 + ((phys ^ (row & 7)) << 3);
        if (kg + 8 <= 784) {
            const float* p = &w1[(size_t)row * 784 + kg];
            a = *(const float4*)p; b = *(const float4*)(p + 4);
        }
        dst = (size_t)tid * 8;
    } else if (tid < 17408) {     // w2k
        const int t2 = tid - 13312;
        const int kt = t2 >> 10, rem = t2 & 1023, row = rem >> 2, phys = rem & 3;
        const int kg = kt * 32 + ((phys ^ (row & 3)) << 3);
        const float* p = &w2[(size_t)row * 128 + kg];
        a = *(const float4*)p; b = *(const float4*)(p + 4);
        dst = (size_t)W2K + (size_t)t2 * 8;
    } else {                      // w3k
        const int t3 = tid - 17408;
        const int row = t3 >> 5, phys = t3 & 31;
        const int kg = (phys ^ (row & 7)) << 3;
        if (row < 10) {
            const float* p = &w3[(size_t)row * 256 + kg];
            a = *(const float4*)p; b = *(const float4*)(p + 4);
        }
        dst = (size_t)W3K + (size_t)t3 * 8;
    }
    *(bf16x8*)&wb[dst] = cvt8(a, b);
}

__global__ __launch_bounds__(TPB, 4) void mnist_v8(
    const float* __restrict__ x,    // [32768,784]
    const float* __restrict__ b1v,  // [128]
    const float* __restrict__ b2v,  // [256]
    const float* __restrict__ b3v,  // [10]
    const short* __restrict__ wb,   // packed bf16 weights
    float* __restrict__ out)        // [32768,10]
{
    __shared__ __align__(16) char smem[80 * 1024];
    float* const xb  = (float*)smem;               // [2][64][64] f32 (32KB)
    short* const wbf = (short*)(smem + 32 * 1024); // [2][128][64] bf16 (32KB)
    short* const h1  = (short*)(smem + 64 * 1024); // [64][128] bf16 (16KB)
    short* const w2l = (short*)smem;               // L2 overlay: [2][256][32] in xb region
    short* const h2  = wbf;                        // [64][256] bf16 overlay (32KB)
    short* const w3l = h1;                         // [16][256] bf16 overlay (8KB)

    const int t    = threadIdx.x;
    const int lane = t & 63;
    const int wv   = t >> 6;        // 0..7
    const int mi   = wv >> 1;       // M-tile: rows mi*16..+15
    const int nh   = wv & 1;        // N-half
    const int l15  = lane & 15;
    const int l4   = lane >> 4;
    const int row0 = blockIdx.x * 64;

    const size_t XLAST = (size_t)32768 * 3136 - 16;

    // --- staging helpers (glds: dest base wave-uniform, +lane*16 implicit) ---
    auto stage_x = [&](int kt, float* dst) {
        #pragma unroll
        for (int p = 0; p < 2; ++p) {
            const int rloc = wv * 8 + p * 4;
            size_t off = (size_t)(row0 + rloc + (lane >> 4)) * 3136
                       + (size_t)kt * 256 + (size_t)(lane & 15) * 16;
            if (off > XLAST) off = XLAST;           // kt=12 tail of last row
            gld16((const char*)x + off, dst + rloc * 64);
        }
    };
    auto stage_w1 = [&](int kt, short* dst) {
        #pragma unroll
        for (int p = 0; p < 2; ++p) {
            const int rloc = wv * 16 + p * 8;
            gld16(wb + (size_t)kt * 8192 + rloc * 64 + lane * 8, dst + rloc * 64);
        }
    };
    auto stage_w2 = [&](int kt, short* dst) {
        #pragma unroll
        for (int p = 0; p < 2; ++p) {
            const int rloc = wv * 32 + p * 16;
            gld16(wb + W2K + (size_t)kt * 8192 + rloc * 32 + lane * 8, dst + rloc * 32);
        }
    };

    // ---------------- prologue: tile 0 ----------------------------------------
    stage_x(0, xb);
    stage_w1(0, wbf);
    __syncthreads();

    // ---------------- Layer 1: 13 K-tiles of 64 -------------------------------
    f32x4 acc1[4];
    #pragma unroll
    for (int nf = 0; nf < 4; ++nf) acc1[nf] = (f32x4){0.f,0.f,0.f,0.f};

    for (int kt = 0; kt < 13; ++kt) {
        const int cur = kt & 1;
        if (kt < 12) {
            stage_x(kt + 1, xb + (cur ^ 1) * 4096);
            stage_w1(kt + 1, wbf + (cur ^ 1) * 8192);
        }
        const float* xt = xb + cur * 4096;
        const short* wt = wbf + cur * 8192;
        #pragma unroll
        for (int kk = 0; kk < 2; ++kk) {
            const float* ap = &xt[(16 * mi + l15) * 64 + kk * 32 + l4 * 8];
            const bf16x8 a = cvt8(*(const float4*)ap, *(const float4*)(ap + 4));
            #pragma unroll
            for (int nf = 0; nf < 4; ++nf) {
                const int rB = nh * 64 + nf * 16 + l15;
                const int phys = (kk * 4 + l4) ^ (rB & 7);
                const bf16x8 b = *(const bf16x8*)&wt[rB * 64 + phys * 8];
                acc1[nf] = __builtin_amdgcn_mfma_f32_16x16x32_bf16(a, b, acc1[nf], 0, 0, 0);
            }
        }
        __syncthreads();
    }

    // ---------------- L1 epilogue + prefetch w2 t0/t1 --------------------------
    stage_w2(0, w2l);
    stage_w2(1, w2l + 8192);
    #pragma unroll
    for (int nf = 0; nf < 4; ++nf) {
        const int c = nh * 64 + nf * 16 + l15;
        const float bc = b1v[c];
        #pragma unroll
        for (int i = 0; i < 4; ++i) {
            const int r = mi * 16 + l4 * 4 + i;
            const float h = fmaxf(acc1[nf][i] + bc, 0.f);
            h1[r * 128 + (((c >> 3) ^ (r & 7)) << 3) + (c & 7)] = f2bf(h);
        }
    }
    __syncthreads();               // h1 visible; w2 t0/t1 drained

    // ---------------- Layer 2: 4 K-tiles of 32 --------------------------------
    bf16x8 a2[4];
    {
        const int row = mi * 16 + l15;
        #pragma unroll
        for (int kk = 0; kk < 4; ++kk)
            a2[kk] = *(const bf16x8*)&h1[row * 128 + (((kk * 4 + l4) ^ (row & 7)) << 3)];
    }
    __syncthreads();               // all waves read a2 -> h1 region dead

    // w3 into h1 region (used in L3; drained by kt0's barrier)
    {
        const int rloc = wv * 2;
        gld16(wb + W3K + rloc * 256 + lane * 8, w3l + rloc * 256);
    }

    f32x4 acc2[8];
    #pragma unroll
    for (int nf = 0; nf < 8; ++nf) acc2[nf] = (f32x4){0.f,0.f,0.f,0.f};

    #pragma unroll
    for (int kt = 0; kt < 4; ++kt) {
        const short* wt2 = w2l + (kt & 1) * 8192;
        #pragma unroll
        for (int nf = 0; nf < 8; ++nf) {
            const int rB = nh * 128 + nf * 16 + l15;
            const int phys = l4 ^ (rB & 3);
            const bf16x8 b = *(const bf16x8*)&wt2[rB * 32 + phys * 8];
            acc2[nf] = __builtin_amdgcn_mfma_f32_16x16x32_bf16(a2[kt], b, acc2[nf], 0, 0, 0);
        }
        __syncthreads();           // all waves done with tile kt (and drains stages)
        if (kt < 2)
            stage_w2(kt + 2, w2l + (kt & 1) * 8192);
    }

    // ---------------- h2 epilogue ----------------------------------------------
    #pragma unroll
    for (int nf = 0; nf < 8; ++nf) {
        const int c = nh * 128 + nf * 16 + l15;
        const float bc = b2v[c];
        #pragma unroll
        for (int i = 0; i < 4; ++i) {
            const int r = mi * 16 + l4 * 4 + i;
            const float h = fmaxf(acc2[nf][i] + bc, 0.f);
            h2[r * 256 + (((c >> 3) ^ (r & 7)) << 3) + (c & 7)] = f2bf(h);
        }
    }
    __syncthreads();

    // ---------------- Layer 3 + log_softmax (nh==0 waves) ----------------------
    if (nh == 0) {
        const int row = mi * 16 + l15;
        f32x4 acc3 = (f32x4){0.f,0.f,0.f,0.f};
        #pragma unroll
        for (int kt = 0; kt < 8; ++kt) {
            const int slot = kt * 4 + l4;
            const bf16x8 a3  = *(const bf16x8*)&h2[row * 256 + ((slot ^ (row & 7)) << 3)];
            const bf16x8 b3r = *(const bf16x8*)&w3l[l15 * 256 + ((slot ^ (l15 & 7)) << 3)];
            acc3 = __builtin_amdgcn_mfma_f32_16x16x32_bf16(a3, b3r, acc3, 0, 0, 0);
        }
        const float b3c = (l15 < 10) ? b3v[l15] : 0.f;
        #pragma unroll
        for (int i = 0; i < 4; ++i) {
            const float v = acc3[i] + b3c;
            float m = (l15 < 10) ? v : -1e30f;
            #pragma unroll
            for (int off = 8; off; off >>= 1) m = fmaxf(m, __shfl_xor(m, off, 16));
            const float e = (l15 < 10) ? expf(v - m) : 0.f;
            float sum = e;
            #pragma unroll
            for (int off = 8; off; off >>= 1) sum += __shfl_xor(sum, off, 16);
            const float ls = m + logf(sum);
            if (l15 < 10) {
                const int r = row0 + mi * 16 + l4 * 4 + i;
                out[(size_t)r * 10 + l15] = v - ls;
            }
        }
    }
}

extern "C" void kernel_launch(void* const* d_in, const int* in_sizes, int n_in,
                              void* d_out, int out_size, void* d_ws, size_t ws_size,
                              hipStream_t stream) {
    const float* x  = (const float*)d_in[0];
    const float* w1 = (const float*)d_in[1];
    const float* b1 = (const float*)d_in[2];
    const float* w2 = (const float*)d_in[3];
    const float* b2 = (const float*)d_in[4];
    const float* w3 = (const float*)d_in[5];
    const float* b3 = (const float*)d_in[6];
    float* out = (float*)d_out;
    short* wb  = (short*)d_ws;   // needs ~287KB scratch

    prep_pack<<<(NCHUNK_TOT + 255) / 256, 256, 0, stream>>>(w1, w2, w3, wb);

    dim3 grid(32768 / 64), block(TPB);
    mnist_v8<<<grid, block, 0, stream>>>(x, b1, b2, b3, wb, out);
}

// Round 10
// 33.432 us; speedup vs baseline: 1.8749x; 1.8749x over previous
//
#include <hip/hip_runtime.h>
#include <hip/hip_bf16.h>
#include <math.h>

// v9 = v8 + x-tile bank-conflict fix (the 19M-conflict bug).
//  - x staged via global_load_lds with PRE-SWIZZLED GLOBAL SOURCE (m173 /
//    rule #21): LDS stays linear, lane reads x[row][ (lane&15 ^ row&15)*4 ],
//    A-read applies the same XOR -> 2-way max (free).
//  - weights pre-packed/pre-swizzled bf16 in d_ws (unchanged from v8).
//  - 512 blocks x 512 thr (8 waves), 80KB LDS -> 2 blocks/CU; 2-phase
//    stage->MFMA->sync per K-tile (proven m230 minimum pipeline).

#define TPB 512

// packed weights in d_ws (shorts):
//  w1k [13 kt][128 row][8 chunk][8]  (chunk pre-XOR'd by row&7)
//  w2k [4 kt][256 row][4 chunk][8]   (pre-XOR'd by row&3)
//  w3k [16 row][32 chunk][8]         (pre-XOR'd by row&7; rows >=10 zero)
#define W2K 106496
#define W3K 139264
#define NCHUNK_TOT 17920   // 13312 + 4096 + 512 (16B chunks)

typedef __attribute__((ext_vector_type(8))) short bf16x8;
typedef __attribute__((ext_vector_type(4))) float f32x4;

static __device__ inline short f2bf(float f) {
    union { float f; unsigned u; } v; v.f = f;
    unsigned r = v.u + 0x7fffu + ((v.u >> 16) & 1u);   // RNE
    return (short)(r >> 16);
}
static __device__ inline bf16x8 cvt8(float4 a, float4 b) {
    union { __hip_bfloat162 h2[4]; bf16x8 v; } u;
    u.h2[0] = __float22bfloat162_rn(make_float2(a.x, a.y));
    u.h2[1] = __float22bfloat162_rn(make_float2(a.z, a.w));
    u.h2[2] = __float22bfloat162_rn(make_float2(b.x, b.y));
    u.h2[3] = __float22bfloat162_rn(make_float2(b.z, b.w));
    return u.v;
}
static __device__ inline void gld16(const void* g, void* l) {
    __builtin_amdgcn_global_load_lds(
        (const __attribute__((address_space(1))) unsigned int*)g,
        (__attribute__((address_space(3))) unsigned int*)l, 16, 0, 0);
}

__global__ void prep_pack(const float* __restrict__ w1,
                          const float* __restrict__ w2,
                          const float* __restrict__ w3,
                          short* __restrict__ wb) {
    const int tid = blockIdx.x * blockDim.x + threadIdx.x;  // one per 16B chunk
    if (tid >= NCHUNK_TOT) return;
    float4 a = make_float4(0,0,0,0), b = a;
    size_t dst;
    if (tid < 13312) {            // w1k
        const int kt = tid >> 10, rem = tid & 1023, row = rem >> 3, phys = rem & 7;
        const int kg = kt * 64 + ((phys ^ (row & 7)) << 3);
        if (kg + 8 <= 784) {
            const float* p = &w1[(size_t)row * 784 + kg];
            a = *(const float4*)p; b = *(const float4*)(p + 4);
        }
        dst = (size_t)tid * 8;
    } else if (tid < 17408) {     // w2k
        const int t2 = tid - 13312;
        const int kt = t2 >> 10, rem = t2 & 1023, row = rem >> 2, phys = rem & 3;
        const int kg = kt * 32 + ((phys ^ (row & 3)) << 3);
        const float* p = &w2[(size_t)row * 128 + kg];
        a = *(const float4*)p; b = *(const float4*)(p + 4);
        dst = (size_t)W2K + (size_t)t2 * 8;
    } else {                      // w3k
        const int t3 = tid - 17408;
        const int row = t3 >> 5, phys = t3 & 31;
        const int kg = (phys ^ (row & 7)) << 3;
        if (row < 10) {
            const float* p = &w3[(size_t)row * 256 + kg];
            a = *(const float4*)p; b = *(const float4*)(p + 4);
        }
        dst = (size_t)W3K + (size_t)t3 * 8;
    }
    *(bf16x8*)&wb[dst] = cvt8(a, b);
}

__global__ __launch_bounds__(TPB, 4) void mnist_v9(
    const float* __restrict__ x,    // [32768,784]
    const float* __restrict__ b1v,  // [128]
    const float* __restrict__ b2v,  // [256]
    const float* __restrict__ b3v,  // [10]
    const short* __restrict__ wb,   // packed bf16 weights
    float* __restrict__ out)        // [32768,10]
{
    __shared__ __align__(16) char smem[80 * 1024];
    float* const xb  = (float*)smem;               // [2][64][64] f32 (32KB), src-swizzled
    short* const wbf = (short*)(smem + 32 * 1024); // [2][128][64] bf16 (32KB)
    short* const h1  = (short*)(smem + 64 * 1024); // [64][128] bf16 (16KB)
    short* const w2l = (short*)smem;               // L2 overlay: [2][256][32] in xb region
    short* const h2  = wbf;                        // [64][256] bf16 overlay (32KB)
    short* const w3l = h1;                         // [16][256] bf16 overlay (8KB)

    const int t    = threadIdx.x;
    const int lane = t & 63;
    const int wv   = t >> 6;        // 0..7
    const int mi   = wv >> 1;       // M-tile: local rows mi*16..+15
    const int nh   = wv & 1;        // N-half
    const int l15  = lane & 15;
    const int l4   = lane >> 4;
    const int row0 = blockIdx.x * 64;

    const size_t XLAST = (size_t)32768 * 3136 - 16;

    // --- staging (glds dest = wave-uniform base + lane*16, LDS linear) -------
    // x: LDS[lrow][slot] holds x[row0+lrow][kt*64 + (slot ^ (lrow&15))*4 ..+4)
    auto stage_x = [&](int kt, float* dst) {
        #pragma unroll
        for (int p = 0; p < 2; ++p) {
            const int rloc = wv * 8 + p * 4;          // 4 rows per glds
            const int rl   = rloc + (lane >> 4);      // this lane's local row
            const int logs = (lane & 15) ^ (rl & 15); // pre-swizzled source slot
            size_t off = (size_t)(row0 + rl) * 3136 + (size_t)kt * 256
                       + (size_t)logs * 16;
            if (off > XLAST) off = XLAST;             // final-row tail clamp
            gld16((const char*)x + off, dst + rloc * 64);
        }
    };
    auto stage_w1 = [&](int kt, short* dst) {
        #pragma unroll
        for (int p = 0; p < 2; ++p) {
            const int rloc = wv * 16 + p * 8;
            gld16(wb + (size_t)kt * 8192 + rloc * 64 + lane * 8, dst + rloc * 64);
        }
    };
    auto stage_w2 = [&](int kt, short* dst) {
        #pragma unroll
        for (int p = 0; p < 2; ++p) {
            const int rloc = wv * 32 + p * 16;
            gld16(wb + W2K + (size_t)kt * 8192 + rloc * 32 + lane * 8, dst + rloc * 32);
        }
    };

    // ---------------- prologue: tile 0 ----------------------------------------
    stage_x(0, xb);
    stage_w1(0, wbf);
    __syncthreads();

    // ---------------- Layer 1: 13 K-tiles of 64 -------------------------------
    f32x4 acc1[4];
    #pragma unroll
    for (int nf = 0; nf < 4; ++nf) acc1[nf] = (f32x4){0.f,0.f,0.f,0.f};

    const int arow = 16 * mi + l15;                   // local A row; arow&15 == l15
    for (int kt = 0; kt < 13; ++kt) {
        const int cur = kt & 1;
        if (kt < 12) {
            stage_x(kt + 1, xb + (cur ^ 1) * 4096);
            stage_w1(kt + 1, wbf + (cur ^ 1) * 8192);
        }
        const float* xt = xb + cur * 4096;
        const short* wt = wbf + cur * 8192;
        #pragma unroll
        for (int kk = 0; kk < 2; ++kk) {
            const int s0 = kk * 8 + l4 * 2;           // logical 16B slot of frag start
            const float4 fa = *(const float4*)&xt[arow * 64 + ((s0 ^ l15) << 2)];
            const float4 fb = *(const float4*)&xt[arow * 64 + (((s0 + 1) ^ l15) << 2)];
            const bf16x8 a = cvt8(fa, fb);
            #pragma unroll
            for (int nf = 0; nf < 4; ++nf) {
                const int rB = nh * 64 + nf * 16 + l15;
                const int phys = (kk * 4 + l4) ^ (rB & 7);
                const bf16x8 b = *(const bf16x8*)&wt[rB * 64 + phys * 8];
                acc1[nf] = __builtin_amdgcn_mfma_f32_16x16x32_bf16(a, b, acc1[nf], 0, 0, 0);
            }
        }
        __syncthreads();
    }

    // ---------------- L1 epilogue + prefetch w2 t0/t1 --------------------------
    stage_w2(0, w2l);
    stage_w2(1, w2l + 8192);
    #pragma unroll
    for (int nf = 0; nf < 4; ++nf) {
        const int c = nh * 64 + nf * 16 + l15;
        const float bc = b1v[c];
        #pragma unroll
        for (int i = 0; i < 4; ++i) {
            const int r = mi * 16 + l4 * 4 + i;
            const float h = fmaxf(acc1[nf][i] + bc, 0.f);
            h1[r * 128 + (((c >> 3) ^ (r & 7)) << 3) + (c & 7)] = f2bf(h);
        }
    }
    __syncthreads();               // h1 visible; w2 t0/t1 drained

    // ---------------- Layer 2: 4 K-tiles of 32 --------------------------------
    bf16x8 a2[4];
    {
        #pragma unroll
        for (int kk = 0; kk < 4; ++kk)
            a2[kk] = *(const bf16x8*)&h1[arow * 128 + (((kk * 4 + l4) ^ (arow & 7)) << 3)];
    }
    __syncthreads();               // all waves read a2 -> h1 region dead

    // w3 into h1 region (used in L3; drained by kt0's barrier)
    {
        const int rloc = wv * 2;
        gld16(wb + W3K + rloc * 256 + lane * 8, w3l + rloc * 256);
    }

    f32x4 acc2[8];
    #pragma unroll
    for (int nf = 0; nf < 8; ++nf) acc2[nf] = (f32x4){0.f,0.f,0.f,0.f};

    #pragma unroll
    for (int kt = 0; kt < 4; ++kt) {
        const short* wt2 = w2l + (kt & 1) * 8192;
        #pragma unroll
        for (int nf = 0; nf < 8; ++nf) {
            const int rB = nh * 128 + nf * 16 + l15;
            const int phys = l4 ^ (rB & 3);
            const bf16x8 b = *(const bf16x8*)&wt2[rB * 32 + phys * 8];
            acc2[nf] = __builtin_amdgcn_mfma_f32_16x16x32_bf16(a2[kt], b, acc2[nf], 0, 0, 0);
        }
        __syncthreads();           // all waves done with tile kt (drains stages)
        if (kt < 2)
            stage_w2(kt + 2, w2l + (kt & 1) * 8192);
    }

    // ---------------- h2 epilogue ----------------------------------------------
    #pragma unroll
    for (int nf = 0; nf < 8; ++nf) {
        const int c = nh * 128 + nf * 16 + l15;
        const float bc = b2v[c];
        #pragma unroll
        for (int i = 0; i < 4; ++i) {
            const int r = mi * 16 + l4 * 4 + i;
            const float h = fmaxf(acc2[nf][i] + bc, 0.f);
            h2[r * 256 + (((c >> 3) ^ (r & 7)) << 3) + (c & 7)] = f2bf(h);
        }
    }
    __syncthreads();

    // ---------------- Layer 3 + log_softmax (nh==0 waves) ----------------------
    if (nh == 0) {
        f32x4 acc3 = (f32x4){0.f,0.f,0.f,0.f};
        #pragma unroll
        for (int kt = 0; kt < 8; ++kt) {
            const int slot = kt * 4 + l4;
            const bf16x8 a3  = *(const bf16x8*)&h2[arow * 256 + ((slot ^ (arow & 7)) << 3)];
            const bf16x8 b3r = *(const bf16x8*)&w3l[l15 * 256 + ((slot ^ (l15 & 7)) << 3)];
            acc3 = __builtin_amdgcn_mfma_f32_16x16x32_bf16(a3, b3r, acc3, 0, 0, 0);
        }
        const float b3c = (l15 < 10) ? b3v[l15] : 0.f;
        #pragma unroll
        for (int i = 0; i < 4; ++i) {
            const float v = acc3[i] + b3c;
            float m = (l15 < 10) ? v : -1e30f;
            #pragma unroll
            for (int off = 8; off; off >>= 1) m = fmaxf(m, __shfl_xor(m, off, 16));
            const float e = (l15 < 10) ? expf(v - m) : 0.f;
            float sum = e;
            #pragma unroll
            for (int off = 8; off; off >>= 1) sum += __shfl_xor(sum, off, 16);
            const float ls = m + logf(sum);
            if (l15 < 10) {
                const int r = row0 + mi * 16 + l4 * 4 + i;
                out[(size_t)r * 10 + l15] = v - ls;
            }
        }
    }
}

extern "C" void kernel_launch(void* const* d_in, const int* in_sizes, int n_in,
                              void* d_out, int out_size, void* d_ws, size_t ws_size,
                              hipStream_t stream) {
    const float* x  = (const float*)d_in[0];
    const float* w1 = (const float*)d_in[1];
    const float* b1 = (const float*)d_in[2];
    const float* w2 = (const float*)d_in[3];
    const float* b2 = (const float*)d_in[4];
    const float* w3 = (const float*)d_in[5];
    const float* b3 = (const float*)d_in[6];
    float* out = (float*)d_out;
    short* wb  = (short*)d_ws;   // needs ~287KB scratch

    prep_pack<<<(NCHUNK_TOT + 255) / 256, 256, 0, stream>>>(w1, w2, w3, wb);

    dim3 grid(32768 / 64), block(TPB);
    mnist_v9<<<grid, block, 0, stream>>>(x, b1, b2, b3, wb, out);
}